// Round 3
// baseline (591.099 us; speedup 1.0000x reference)
//
#include <hip/hip_runtime.h>
#include <hip/hip_bf16.h>

#define NB 2
#define NN 512
#define ND 64
#define NH 128
#define BTS (NH + 8)   // 136 shorts: +16B row pad

typedef __attribute__((ext_vector_type(8))) short short8;
typedef __attribute__((ext_vector_type(4))) float f32x4;

__device__ __forceinline__ short f2s(float x) {
    __hip_bfloat16 h = __float2bfloat16(x);
    return *reinterpret_cast<short*>(&h);
}

__device__ __forceinline__ short8 cvt8v(f32x4 a, f32x4 b) {
    short8 r;
    r[0] = f2s(a[0]); r[1] = f2s(a[1]); r[2] = f2s(a[2]); r[3] = f2s(a[3]);
    r[4] = f2s(b[0]); r[5] = f2s(b[1]); r[6] = f2s(b[2]); r[7] = f2s(b[3]);
    return r;
}

__device__ __forceinline__ short8 cvt8(const float* p) {
    return cvt8v(*(const f32x4*)p, *(const f32x4*)(p + 4));
}

// ---------------------------------------------------------------------------
// One block per (b,i). Fuses bias (MFMA C-init), edge_h GEMM+relu
// (swapped-operand MFMA -> contiguous dwordx4 stores), message reduce,
// and the ending MLP.
// R3: R1 structure + 2-deep ef prefetch (raw f32x4, +16 VGPR) +
// launch_bounds(256,4) to pin VGPR<=128 (4 blocks/CU). Plain stores
// (R2's nt stores caused 1.33x write amplification); nt loads kept on ef.
// ---------------------------------------------------------------------------
__global__ __launch_bounds__(256, 4) void fused_kernel(
    const float* __restrict__ ef,       // B,N,N,64 fp32
    const float* __restrict__ node,     // B,N,64 fp32
    const float* __restrict__ adj,      // B,N,N fp32
    const float* __restrict__ W_edge,   // 192,128 fp32
    const float* __restrict__ b_edge,   // 128 fp32
    const float* __restrict__ W_feat,   // 192,128 fp32
    const float* __restrict__ b_feat,   // 128 fp32
    float* __restrict__ edge_out,       // B,N,N,128 fp32
    float* __restrict__ ending)         // B,N,128 fp32
{
    __shared__ short BT[NH * BTS];      // BT[h][k] = bf16(Bmat[k][h]); Bmat = [W3;W2]
    __shared__ float nrow_s[ND];
    __shared__ float bias_s[NH];
    __shared__ float red_s[NH];
    __shared__ float msgbuf[4][NH];
    __shared__ float msg_s[NH];

    int blk = blockIdx.x;               // b*N + i
    int b = blk >> 9;
    int tid = threadIdx.x;

    // Stage BT, coalesced on W_edge reads (consecutive tid -> consecutive h).
    for (int t = tid; t < NH * NH; t += 256) {
        int k = t >> 7;                 // K index (0..127)
        int h = t & 127;                // H index
        int row = (k < ND) ? (2 * ND + k) : k;   // k<64 -> W3 row, else W2 row
        BT[h * BTS + k] = f2s(W_edge[row * NH + h]);
    }
    if (tid < ND) nrow_s[tid] = node[(size_t)blk * ND + tid];
    __syncthreads();

    // bias_s[h] = b_edge[h] + sum_d node_i[d]*W1[d][h], d-range split over 2 halves
    {
        int h = tid & 127, half = tid >> 7;
        float acc = 0.f;
        #pragma unroll
        for (int d = half * 32; d < half * 32 + 32; d++)
            acc += nrow_s[d] * W_edge[d * NH + h];
        if (half) red_s[h] = acc;
        __syncthreads();
        if (!half) bias_s[h] = acc + red_s[h] + b_edge[h];
        __syncthreads();
    }

    int lane = tid & 63, wave = tid >> 6;
    int m = lane & 15, quad = lane >> 4;

    float msg_l[32];                     // msg partial for h = ht*16 + quad*4 + r
    #pragma unroll
    for (int t = 0; t < 32; t++) msg_l[t] = 0.f;

    const float* adjrow = adj + (size_t)blk * NN;
    float* outbase = edge_out + (size_t)blk * NN * NH;

    // Prefetch ef for c=0 (raw fp32; nt: zero-reuse stream).
    f32x4 pref[4];
    {
        const float* efp = ef + ((size_t)blk * NN + wave * 128 + m) * ND + quad * 8;
        pref[0] = __builtin_nontemporal_load((const f32x4*)efp);
        pref[1] = __builtin_nontemporal_load((const f32x4*)(efp + 4));
        pref[2] = __builtin_nontemporal_load((const f32x4*)(efp + 32));
        pref[3] = __builtin_nontemporal_load((const f32x4*)(efp + 36));
    }

    for (int c = 0; c < 8; c++) {
        int jm = wave * 128 + c * 16 + m;        // this lane's j row
        const float* ndp = node + ((size_t)b * NN + jm) * ND;
        short8 af[4];
        af[0] = cvt8v(pref[0], pref[1]);         // k 0..31   (edge feats)
        af[1] = cvt8v(pref[2], pref[3]);         // k 32..63
        af[2] = cvt8(ndp + quad * 8);            // k 64..95  (node_j, L2-hot)
        af[3] = cvt8(ndp + 32 + quad * 8);       // k 96..127
        float adjv = adjrow[jm];

        // Issue next c's ef loads now; HBM latency hides under MFMA/store phase.
        if (c < 7) {
            const float* efpn = ef + ((size_t)blk * NN + jm + 16) * ND + quad * 8;
            pref[0] = __builtin_nontemporal_load((const f32x4*)efpn);
            pref[1] = __builtin_nontemporal_load((const f32x4*)(efpn + 4));
            pref[2] = __builtin_nontemporal_load((const f32x4*)(efpn + 32));
            pref[3] = __builtin_nontemporal_load((const f32x4*)(efpn + 36));
        }

        float* outrow = outbase + (size_t)jm * NH;
        #pragma unroll
        for (int ht = 0; ht < 8; ht++) {
            // C-init = bias (broadcast LDS read within quad group)
            f32x4 acc = *(const f32x4*)(bias_s + ht * 16 + quad * 4);
            const short* bt = BT + (ht * 16 + m) * BTS;
            #pragma unroll
            for (int kf = 0; kf < 4; kf++) {
                short8 bfr = *(const short8*)(bt + kf * 32 + quad * 8);
                // swapped operands: D[row=h (quad*4+r)][col=j (m)]
                acc = __builtin_amdgcn_mfma_f32_16x16x32_bf16(bfr, af[kf], acc, 0, 0, 0);
            }
            f32x4 v;
            #pragma unroll
            for (int r = 0; r < 4; r++) {
                v[r] = fmaxf(acc[r], 0.f);
                msg_l[ht * 4 + r] += adjv * v[r];
            }
            // 16B/lane; quad-group covers h = ht*16 .. ht*16+15 contiguously
            *(f32x4*)(outrow + ht * 16 + quad * 4) = v;
        }
    }

    // Reduce msg over the 16 m-lanes (j runs over m within each quad group).
    #pragma unroll
    for (int t = 0; t < 32; t++) {
        float v = msg_l[t];
        v += __shfl_xor(v, 1, 64);
        v += __shfl_xor(v, 2, 64);
        v += __shfl_xor(v, 4, 64);
        v += __shfl_xor(v, 8, 64);
        msg_l[t] = v;
    }
    if (m == 0) {
        #pragma unroll
        for (int ht = 0; ht < 8; ht++)
            #pragma unroll
            for (int r = 0; r < 4; r++)
                msgbuf[wave][ht * 16 + quad * 4 + r] = msg_l[ht * 4 + r];
    }
    __syncthreads();
    if (tid < NH)
        msg_s[tid] = msgbuf[0][tid] + msgbuf[1][tid] + msgbuf[2][tid] + msgbuf[3][tid];
    __syncthreads();

    // ending[k] = relu(msg@Wf1[:,k] + node_i@Wf2[:,k] + b_feat[k]); 2-half split
    {
        int k = tid & 127, half = tid >> 7;
        float acc = 0.f;
        #pragma unroll 4
        for (int hh = half * 64; hh < half * 64 + 64; hh++)
            acc += msg_s[hh] * W_feat[hh * NH + k];
        #pragma unroll 4
        for (int d = half * 32; d < half * 32 + 32; d++)
            acc += nrow_s[d] * W_feat[(NH + d) * NH + k];
        if (half) red_s[k] = acc;
        __syncthreads();
        if (!half) ending[(size_t)blk * NH + k] = fmaxf(acc + red_s[k] + b_feat[k], 0.f);
    }
}

// ---------------------------------------------------------------------------
extern "C" void kernel_launch(void* const* d_in, const int* in_sizes, int n_in,
                              void* d_out, int out_size, void* d_ws, size_t ws_size,
                              hipStream_t stream)
{
    const float* node   = (const float*)d_in[0];
    const float* adj    = (const float*)d_in[1];
    const float* tgt    = (const float*)d_in[2];
    const float* ef     = (const float*)d_in[3];
    // d_in[4] = node_mask (unused by reference)
    const float* W_edge = (const float*)d_in[5];
    const float* b_edge = (const float*)d_in[6];
    const float* W_feat = (const float*)d_in[7];
    const float* b_feat = (const float*)d_in[8];

    float* out_ending = (float*)d_out;                           // B*N*H
    float* out_edge   = out_ending + (size_t)NB * NN * NH;       // B*N*N*H
    float* out_tgt    = out_edge + (size_t)NB * NN * NN * NH;    // B*N*D

    fused_kernel<<<NB * NN, 256, 0, stream>>>(ef, node, adj, W_edge, b_edge,
                                              W_feat, b_feat, out_edge, out_ending);
    hipMemcpyAsync(out_tgt, tgt, (size_t)NB * NN * ND * sizeof(float),
                   hipMemcpyDeviceToDevice, stream);
}

// Round 4
// 422.707 us; speedup vs baseline: 1.3984x; 1.3984x over previous
//
#include <hip/hip_runtime.h>
#include <hip/hip_bf16.h>

#define NB 2
#define NN 512
#define ND 64
#define NH 128
#define BTS (NH + 8)   // 136: 16B-aligned rows, conflict-managed

typedef __attribute__((ext_vector_type(8))) short short8;
typedef __attribute__((ext_vector_type(4))) float f32x4;

__device__ __forceinline__ short f2s(float x) {
    __hip_bfloat16 h = __float2bfloat16(x);
    return *reinterpret_cast<short*>(&h);
}

__device__ __forceinline__ short8 cvt8v(f32x4 a, f32x4 b) {
    short8 r;
    r[0] = f2s(a[0]); r[1] = f2s(a[1]); r[2] = f2s(a[2]); r[3] = f2s(a[3]);
    r[4] = f2s(b[0]); r[5] = f2s(b[1]); r[6] = f2s(b[2]); r[7] = f2s(b[3]);
    return r;
}

__device__ __forceinline__ short8 cvt8(const float* p) {
    return cvt8v(*(const f32x4*)p, *(const f32x4*)(p + 4));
}

__device__ __forceinline__ short8 cvt8_nt(const float* p) {
    return cvt8v(__builtin_nontemporal_load((const f32x4*)p),
                 __builtin_nontemporal_load((const f32x4*)(p + 4)));
}

// ---------------------------------------------------------------------------
// One block per (b,i). Fuses: bias = node_i@W1 + b_edge (as MFMA C-init),
// edge_h GEMM+relu (swapped-operand MFMA -> contiguous dwordx4 stores),
// message = adj-weighted row sum (in-register + shfl reduce),
// ending = relu(msg@Wf1 + node_i@Wf2 + b_feat).
// R4 = exact R1 structure (the measured optimum: R2's reg-blocking hit the
// 212-VGPR occupancy cliff; R3's launch_bounds pin hit the spill cliff at 64)
// + nontemporal flag on the zero-reuse ef loads only (no VGPR cost).
// ---------------------------------------------------------------------------
__global__ __launch_bounds__(256) void fused_kernel(
    const float* __restrict__ ef,       // B,N,N,64 fp32
    const float* __restrict__ node,     // B,N,64 fp32
    const float* __restrict__ adj,      // B,N,N fp32
    const float* __restrict__ W_edge,   // 192,128 fp32
    const float* __restrict__ b_edge,   // 128 fp32
    const float* __restrict__ W_feat,   // 192,128 fp32
    const float* __restrict__ b_feat,   // 128 fp32
    float* __restrict__ edge_out,       // B,N,N,128 fp32
    float* __restrict__ ending)         // B,N,128 fp32
{
    __shared__ short BT[NH * BTS];      // BT[h][k] = bf16(Bmat[k][h]); Bmat = [W3;W2]
    __shared__ float nrow_s[ND];
    __shared__ float bias_s[NH];
    __shared__ float red_s[NH];
    __shared__ float msgbuf[4][NH];
    __shared__ float msg_s[NH];

    int blk = blockIdx.x;               // b*N + i
    int b = blk >> 9;
    int tid = threadIdx.x;

    // Stage BT, coalesced on W_edge reads (consecutive tid -> consecutive h).
    for (int t = tid; t < NH * NH; t += 256) {
        int k = t >> 7;                 // K index (0..127)
        int h = t & 127;                // H index
        int row = (k < ND) ? (2 * ND + k) : k;   // k<64 -> W3 row, else W2 row
        BT[h * BTS + k] = f2s(W_edge[row * NH + h]);
    }
    if (tid < ND) nrow_s[tid] = node[(size_t)blk * ND + tid];
    __syncthreads();

    // bias_s[h] = b_edge[h] + sum_d node_i[d]*W1[d][h], split d-range over 2 halves
    {
        int h = tid & 127, half = tid >> 7;
        float acc = 0.f;
        #pragma unroll
        for (int d = half * 32; d < half * 32 + 32; d++)
            acc += nrow_s[d] * W_edge[d * NH + h];
        if (half) red_s[h] = acc;
        __syncthreads();
        if (!half) bias_s[h] = acc + red_s[h] + b_edge[h];
        __syncthreads();
    }

    int lane = tid & 63, wave = tid >> 6;
    int m = lane & 15, quad = lane >> 4;

    float msg_l[32];                     // msg partial for h = ht*16 + quad*4 + r
    #pragma unroll
    for (int t = 0; t < 32; t++) msg_l[t] = 0.f;

    const float* adjrow = adj + (size_t)blk * NN;
    float* outbase = edge_out + (size_t)blk * NN * NH;

    for (int c = 0; c < 8; c++) {
        int jm = wave * 128 + c * 16 + m;        // this lane's j row
        const float* efp = ef + ((size_t)blk * NN + jm) * ND;
        const float* ndp = node + ((size_t)b * NN + jm) * ND;
        short8 af[4];
        af[0] = cvt8_nt(efp + quad * 8);         // k 0..31   (edge feats, nt stream)
        af[1] = cvt8_nt(efp + 32 + quad * 8);    // k 32..63
        af[2] = cvt8(ndp + quad * 8);            // k 64..95  (node_j feats, L2-hot)
        af[3] = cvt8(ndp + 32 + quad * 8);       // k 96..127
        float adjv = adjrow[jm];

        float* outrow = outbase + (size_t)jm * NH;
        #pragma unroll
        for (int ht = 0; ht < 8; ht++) {
            // C-init = bias (broadcast LDS read: 16 lanes/quad same addr)
            f32x4 acc = *(const f32x4*)(bias_s + ht * 16 + quad * 4);
            const short* bt = BT + (ht * 16 + m) * BTS;
            #pragma unroll
            for (int kf = 0; kf < 4; kf++) {
                short8 bfr = *(const short8*)(bt + kf * 32 + quad * 8);
                // swapped operands: D[row=h (quad*4+r)][col=j (m)]
                acc = __builtin_amdgcn_mfma_f32_16x16x32_bf16(bfr, af[kf], acc, 0, 0, 0);
            }
            f32x4 v;
            #pragma unroll
            for (int r = 0; r < 4; r++) {
                v[r] = fmaxf(acc[r], 0.f);
                msg_l[ht * 4 + r] += adjv * v[r];
            }
            // 16B/lane, contiguous 64B per quad-group: h = ht*16 + quad*4 ..+3
            *(f32x4*)(outrow + ht * 16 + quad * 4) = v;
        }
    }

    // Reduce msg over the 16 m-lanes (xor bits 0..3 stay within quad group).
    #pragma unroll
    for (int t = 0; t < 32; t++) {
        float v = msg_l[t];
        v += __shfl_xor(v, 1, 64);
        v += __shfl_xor(v, 2, 64);
        v += __shfl_xor(v, 4, 64);
        v += __shfl_xor(v, 8, 64);
        msg_l[t] = v;
    }
    if (m == 0) {
        #pragma unroll
        for (int ht = 0; ht < 8; ht++)
            #pragma unroll
            for (int r = 0; r < 4; r++)
                msgbuf[wave][ht * 16 + quad * 4 + r] = msg_l[ht * 4 + r];
    }
    __syncthreads();
    if (tid < NH)
        msg_s[tid] = msgbuf[0][tid] + msgbuf[1][tid] + msgbuf[2][tid] + msgbuf[3][tid];
    __syncthreads();

    // ending[k] = relu(msg@Wf1[:,k] + node_i@Wf2[:,k] + b_feat[k]); 2-half split
    {
        int k = tid & 127, half = tid >> 7;
        float acc = 0.f;
        #pragma unroll 4
        for (int hh = half * 64; hh < half * 64 + 64; hh++)
            acc += msg_s[hh] * W_feat[hh * NH + k];
        #pragma unroll 4
        for (int d = half * 32; d < half * 32 + 32; d++)
            acc += nrow_s[d] * W_feat[(NH + d) * NH + k];
        if (half) red_s[k] = acc;
        __syncthreads();
        if (!half) ending[(size_t)blk * NH + k] = fmaxf(acc + red_s[k] + b_feat[k], 0.f);
    }
}

// ---------------------------------------------------------------------------
extern "C" void kernel_launch(void* const* d_in, const int* in_sizes, int n_in,
                              void* d_out, int out_size, void* d_ws, size_t ws_size,
                              hipStream_t stream)
{
    const float* node   = (const float*)d_in[0];
    const float* adj    = (const float*)d_in[1];
    const float* tgt    = (const float*)d_in[2];
    const float* ef     = (const float*)d_in[3];
    // d_in[4] = node_mask (unused by reference)
    const float* W_edge = (const float*)d_in[5];
    const float* b_edge = (const float*)d_in[6];
    const float* W_feat = (const float*)d_in[7];
    const float* b_feat = (const float*)d_in[8];

    float* out_ending = (float*)d_out;                           // B*N*H
    float* out_edge   = out_ending + (size_t)NB * NN * NH;       // B*N*N*H
    float* out_tgt    = out_edge + (size_t)NB * NN * NN * NH;    // B*N*D

    fused_kernel<<<NB * NN, 256, 0, stream>>>(ef, node, adj, W_edge, b_edge,
                                              W_feat, b_feat, out_edge, out_ending);
    hipMemcpyAsync(out_tgt, tgt, (size_t)NB * NN * ND * sizeof(float),
                   hipMemcpyDeviceToDevice, stream);
}

// Round 5
// 415.439 us; speedup vs baseline: 1.4228x; 1.0175x over previous
//
#include <hip/hip_runtime.h>
#include <hip/hip_bf16.h>

#define NB 2
#define NN 512
#define ND 64
#define NH 128
#define BTS (NH + 8)   // 136: 16B-aligned rows, conflict-managed

typedef __attribute__((ext_vector_type(8))) short short8;
typedef __attribute__((ext_vector_type(4))) float f32x4;

__device__ __forceinline__ short f2s(float x) {
    __hip_bfloat16 h = __float2bfloat16(x);
    return *reinterpret_cast<short*>(&h);
}

__device__ __forceinline__ short8 cvt8(const float* p) {
    f32x4 a = *(const f32x4*)p;
    f32x4 b = *(const f32x4*)(p + 4);
    short8 r;
    r[0] = f2s(a[0]); r[1] = f2s(a[1]); r[2] = f2s(a[2]); r[3] = f2s(a[3]);
    r[4] = f2s(b[0]); r[5] = f2s(b[1]); r[6] = f2s(b[2]); r[7] = f2s(b[3]);
    return r;
}

// ---------------------------------------------------------------------------
// One block per (b,i). Fuses: bias = node_i@W1 + b_edge (as MFMA C-init),
// edge_h GEMM+relu (swapped-operand MFMA -> contiguous dwordx4 stores),
// message = adj-weighted row sum (in-register + shfl reduce),
// ending = relu(msg@Wf1 + node_i@Wf2 + b_feat).
// R5 = exact R1 (measured optimum). Design-space boundaries measured:
//   R2 c-blocking -> 212 VGPR occupancy cliff (2 blk/CU, 2.4 TB/s);
//   R3 launch_bounds(256,4) -> spill cliff (VGPR=64, ~550 MB scratch);
//   R4 nt ef loads -> forfeits L3 retention of ef, +7 us.
// Natural compiler allocation + plain cached loads is the optimum.
// ---------------------------------------------------------------------------
__global__ __launch_bounds__(256) void fused_kernel(
    const float* __restrict__ ef,       // B,N,N,64 fp32
    const float* __restrict__ node,     // B,N,64 fp32
    const float* __restrict__ adj,      // B,N,N fp32
    const float* __restrict__ W_edge,   // 192,128 fp32
    const float* __restrict__ b_edge,   // 128 fp32
    const float* __restrict__ W_feat,   // 192,128 fp32
    const float* __restrict__ b_feat,   // 128 fp32
    float* __restrict__ edge_out,       // B,N,N,128 fp32
    float* __restrict__ ending)         // B,N,128 fp32
{
    __shared__ short BT[NH * BTS];      // BT[h][k] = bf16(Bmat[k][h]); Bmat = [W3;W2]
    __shared__ float nrow_s[ND];
    __shared__ float bias_s[NH];
    __shared__ float red_s[NH];
    __shared__ float msgbuf[4][NH];
    __shared__ float msg_s[NH];

    int blk = blockIdx.x;               // b*N + i
    int b = blk >> 9;
    int tid = threadIdx.x;

    // Stage BT, coalesced on W_edge reads (consecutive tid -> consecutive h).
    for (int t = tid; t < NH * NH; t += 256) {
        int k = t >> 7;                 // K index (0..127)
        int h = t & 127;                // H index
        int row = (k < ND) ? (2 * ND + k) : k;   // k<64 -> W3 row, else W2 row
        BT[h * BTS + k] = f2s(W_edge[row * NH + h]);
    }
    if (tid < ND) nrow_s[tid] = node[(size_t)blk * ND + tid];
    __syncthreads();

    // bias_s[h] = b_edge[h] + sum_d node_i[d]*W1[d][h], split d-range over 2 halves
    {
        int h = tid & 127, half = tid >> 7;
        float acc = 0.f;
        #pragma unroll
        for (int d = half * 32; d < half * 32 + 32; d++)
            acc += nrow_s[d] * W_edge[d * NH + h];
        if (half) red_s[h] = acc;
        __syncthreads();
        if (!half) bias_s[h] = acc + red_s[h] + b_edge[h];
        __syncthreads();
    }

    int lane = tid & 63, wave = tid >> 6;
    int m = lane & 15, quad = lane >> 4;

    float msg_l[32];                     // msg partial for h = ht*16 + quad*4 + r
    #pragma unroll
    for (int t = 0; t < 32; t++) msg_l[t] = 0.f;

    const float* adjrow = adj + (size_t)blk * NN;
    float* outbase = edge_out + (size_t)blk * NN * NH;

    for (int c = 0; c < 8; c++) {
        int jm = wave * 128 + c * 16 + m;        // this lane's j row
        const float* efp = ef + ((size_t)blk * NN + jm) * ND;
        const float* ndp = node + ((size_t)b * NN + jm) * ND;
        short8 af[4];
        af[0] = cvt8(efp + quad * 8);            // k 0..31   (edge feats)
        af[1] = cvt8(efp + 32 + quad * 8);       // k 32..63
        af[2] = cvt8(ndp + quad * 8);            // k 64..95  (node_j feats, L2-hot)
        af[3] = cvt8(ndp + 32 + quad * 8);       // k 96..127
        float adjv = adjrow[jm];

        float* outrow = outbase + (size_t)jm * NH;
        #pragma unroll
        for (int ht = 0; ht < 8; ht++) {
            // C-init = bias (broadcast LDS read: 16 lanes/quad same addr)
            f32x4 acc = *(const f32x4*)(bias_s + ht * 16 + quad * 4);
            const short* bt = BT + (ht * 16 + m) * BTS;
            #pragma unroll
            for (int kf = 0; kf < 4; kf++) {
                short8 bfr = *(const short8*)(bt + kf * 32 + quad * 8);
                // swapped operands: D[row=h (quad*4+r)][col=j (m)]
                acc = __builtin_amdgcn_mfma_f32_16x16x32_bf16(bfr, af[kf], acc, 0, 0, 0);
            }
            f32x4 v;
            #pragma unroll
            for (int r = 0; r < 4; r++) {
                v[r] = fmaxf(acc[r], 0.f);
                msg_l[ht * 4 + r] += adjv * v[r];
            }
            // 16B/lane, contiguous 64B per quad-group: h = ht*16 + quad*4 ..+3
            *(f32x4*)(outrow + ht * 16 + quad * 4) = v;
        }
    }

    // Reduce msg over the 16 m-lanes (xor bits 0..3 stay within quad group).
    #pragma unroll
    for (int t = 0; t < 32; t++) {
        float v = msg_l[t];
        v += __shfl_xor(v, 1, 64);
        v += __shfl_xor(v, 2, 64);
        v += __shfl_xor(v, 4, 64);
        v += __shfl_xor(v, 8, 64);
        msg_l[t] = v;
    }
    if (m == 0) {
        #pragma unroll
        for (int ht = 0; ht < 8; ht++)
            #pragma unroll
            for (int r = 0; r < 4; r++)
                msgbuf[wave][ht * 16 + quad * 4 + r] = msg_l[ht * 4 + r];
    }
    __syncthreads();
    if (tid < NH)
        msg_s[tid] = msgbuf[0][tid] + msgbuf[1][tid] + msgbuf[2][tid] + msgbuf[3][tid];
    __syncthreads();

    // ending[k] = relu(msg@Wf1[:,k] + node_i@Wf2[:,k] + b_feat[k]); 2-half split
    {
        int k = tid & 127, half = tid >> 7;
        float acc = 0.f;
        #pragma unroll 4
        for (int hh = half * 64; hh < half * 64 + 64; hh++)
            acc += msg_s[hh] * W_feat[hh * NH + k];
        #pragma unroll 4
        for (int d = half * 32; d < half * 32 + 32; d++)
            acc += nrow_s[d] * W_feat[(NH + d) * NH + k];
        if (half) red_s[k] = acc;
        __syncthreads();
        if (!half) ending[(size_t)blk * NH + k] = fmaxf(acc + red_s[k] + b_feat[k], 0.f);
    }
}

// ---------------------------------------------------------------------------
extern "C" void kernel_launch(void* const* d_in, const int* in_sizes, int n_in,
                              void* d_out, int out_size, void* d_ws, size_t ws_size,
                              hipStream_t stream)
{
    const float* node   = (const float*)d_in[0];
    const float* adj    = (const float*)d_in[1];
    const float* tgt    = (const float*)d_in[2];
    const float* ef     = (const float*)d_in[3];
    // d_in[4] = node_mask (unused by reference)
    const float* W_edge = (const float*)d_in[5];
    const float* b_edge = (const float*)d_in[6];
    const float* W_feat = (const float*)d_in[7];
    const float* b_feat = (const float*)d_in[8];

    float* out_ending = (float*)d_out;                           // B*N*H
    float* out_edge   = out_ending + (size_t)NB * NN * NH;       // B*N*N*H
    float* out_tgt    = out_edge + (size_t)NB * NN * NN * NH;    // B*N*D

    fused_kernel<<<NB * NN, 256, 0, stream>>>(ef, node, adj, W_edge, b_edge,
                                              W_feat, b_feat, out_edge, out_ending);
    hipMemcpyAsync(out_tgt, tgt, (size_t)NB * NN * ND * sizeof(float),
                   hipMemcpyDeviceToDevice, stream);
}